// Round 9
// baseline (194.305 us; speedup 1.0000x reference)
//
#include <hip/hip_runtime.h>
#include <hip/hip_bf16.h>

typedef __attribute__((ext_vector_type(8))) short short8;
typedef __attribute__((ext_vector_type(4))) float floatx4;

struct ushort4v { unsigned short x, y, z, w; };

static __device__ __forceinline__ unsigned short f2bf(float f) {
    __hip_bfloat16 h = __float2bfloat16(f);
    return *reinterpret_cast<unsigned short*>(&h);
}

static __device__ __forceinline__ float bf2f(unsigned short u) {
    unsigned int v = ((unsigned int)u) << 16;
    return *reinterpret_cast<float*>(&v);
}

#define ASYNC_COPY16(gsrc, ldst)                                                            \
    __builtin_amdgcn_global_load_lds((const __attribute__((address_space(1))) void*)(gsrc), \
                                     (__attribute__((address_space(3))) void*)(ldst), 16, 0, 0)

static __device__ __forceinline__ void block_barrier() {
    asm volatile("" ::: "memory");
    __builtin_amdgcn_s_barrier();
    asm volatile("" ::: "memory");
}

// ---------------------------------------------------------------------------
__global__ void mask_detect(const unsigned char* __restrict__ m, int* __restrict__ flag) {
    __shared__ int s_or;
    if (threadIdx.x == 0) s_or = 0;
    __syncthreads();
    int acc = 0;
    for (int i = threadIdx.x; i < 8192; i += 256)
        if (i & 3) acc |= m[i];
    atomicOr(&s_or, acc);
    __syncthreads();
    if (threadIdx.x == 0) *flag = (s_or != 0) ? 1 : 0;  // 1 => u8 encoding
}

// keep[i] = 1.0f if attended, 0.0f if masked query row. exp(score*0)=1 for the
// whole row -> exactly-uniform softmax, identical to the reference where
// score*(1/32) + (-1e9) rounds to exactly -1e9 in fp32.
__global__ void mask_expand(const void* __restrict__ m, const int* __restrict__ flag,
                            float* __restrict__ keep, int n) {
    int i = blockIdx.x * 256 + threadIdx.x;
    if (i >= n) return;
    bool on;
    if (*flag)
        on = ((const unsigned char*)m)[i] != 0;
    else
        on = ((const int*)m)[i] != 0;
    keep[i] = on ? 1.0f : 0.0f;
}

// ---------------------------------------------------------------------------
__global__ __launch_bounds__(256) void convert_f32_bf16(const float* __restrict__ in,
                                                        unsigned short* __restrict__ out, long n4) {
    long i = (long)blockIdx.x * 256 + threadIdx.x;
    if (i >= n4) return;
    float4 v = ((const float4*)in)[i];
    ushort4v o;
    o.x = f2bf(v.x); o.y = f2bf(v.y); o.z = f2bf(v.z); o.w = f2bf(v.w);
    ((ushort4v*)out)[i] = o;
}

// ---------------------------------------------------------------------------
__global__ void transpose_w_kernel(const float* __restrict__ w0, const float* __restrict__ w1,
                                   const float* __restrict__ w2, unsigned short* __restrict__ out) {
    __shared__ float t[32][33];
    const float* w = blockIdx.z == 0 ? w0 : (blockIdx.z == 1 ? w1 : w2);
    unsigned short* o = out + (long)blockIdx.z * 1024 * 1024;
    int c0 = blockIdx.x * 32, r0 = blockIdx.y * 32;
    for (int i = threadIdx.y; i < 32; i += 8)
        t[i][threadIdx.x] = w[(long)(r0 + i) * 1024 + c0 + threadIdx.x];
    __syncthreads();
    for (int i = threadIdx.y; i < 32; i += 8)
        o[(long)(c0 + i) * 1024 + r0 + threadIdx.x] = f2bf(t[threadIdx.x][i]);
}

// ---------------------------------------------------------------------------
__global__ void transpose_bf16(const unsigned short* __restrict__ in, unsigned short* __restrict__ out,
                               int rows, int cols, long sIn, long sOut) {
    __shared__ unsigned short t[32][34];
    const unsigned short* ib = in + (long)blockIdx.z * sIn;
    unsigned short* ob = out + (long)blockIdx.z * sOut;
    int c0 = blockIdx.x * 32, r0 = blockIdx.y * 32;
    for (int i = threadIdx.y; i < 32; i += 8)
        t[i][threadIdx.x] = ib[(long)(r0 + i) * cols + c0 + threadIdx.x];
    __syncthreads();
    for (int i = threadIdx.y; i < 32; i += 8)
        ob[(long)(c0 + i) * rows + r0 + threadIdx.x] = t[threadIdx.x][i];
}

// ---------------------------------------------------------------------------
// 256x256 phase-scheduled GEMM (m201-class): C = A[M,K] * BT[N,K]^T, bf16/fp32.
// BK=64, 8 waves (wm=wid>>2, wn=wid&3); per-wave rows mh*128+wm*64 (M-halves
// interleaved across phases so phase mh touches only A-half mh).
// LDS: 2 dbuf x {A[256][64] | B[256][64]} = 128 KB; 1 block/CU.
// Per K-tile: 4 phases (ks,mh) = {0,0},{0,1},{1,0},{1,1}; each phase:
//   8 ds_read_b128 -> stage one 16KB unit of kt+1 (2 gload_lds) -> barrier
//   -> lgkmcnt(0)+sched_barrier -> setprio(1) -> 16 MFMA -> setprio(0)
//   -> [counted vmcnt] -> barrier
// Stage unit order u=[Ah0,Bh0,Bh1,Ah1]; vmcnt(2) at end of p0 (publishes Ah1
// for p1) and end of p3 (publishes Ah0,Bh0,Bh1 for next tile's p0); in-flight
// never drains to 0 except the final tile. Swizzle: HW-verified 128B-row
// involution c ^= (row&7)<<4, applied to pre-swizzled global source AND read.
// EPI 0: bf16 C; EPI 1: bf16 exp(acc*scale*keep[row]).
// ---------------------------------------------------------------------------
template <int EPI>
static __device__ __forceinline__ void gemm256_body(const unsigned short* __restrict__ A,
                                                    const unsigned short* __restrict__ B,
                                                    void* __restrict__ Cv,
                                                    const float* __restrict__ aux,
                                                    int K, int lda, int ldb, int ldc,
                                                    long sA, long sB, long sC, long sAux,
                                                    float scale) {
    constexpr int BUF = 65536;  // A(32KB) + B(32KB) per K-tile
    __shared__ char sm[2 * BUF];
    const int tid = threadIdx.x;
    const int wid = tid >> 6, lane = tid & 63;
    const int wm = wid >> 2, wn = wid & 3;
    const int fr = lane & 15, fk = lane >> 4;
    const long m0 = (long)blockIdx.x * 256;
    const long n0 = (long)blockIdx.y * 256;
    const unsigned short* Ab = A + (long)blockIdx.z * sA + m0 * lda;
    const unsigned short* Bb = B + (long)blockIdx.z * sB + n0 * ldb;
    const int NKT = K >> 6;

    floatx4 acc[8][4] = {};  // [mh*4+mi][ni]

    // stage one 16KB unit: u=0:Ah0 1:Bh0 2:Bh1 3:Ah1 of K-tile kt -> buf[kt&1]
    auto stage_unit = [&](int kt, int u) {
        const int isB  = (u == 1 || u == 2) ? 1 : 0;
        const int half = (u >= 2) ? 1 : 0;
        char* dst = sm + (kt & 1) * BUF + isB * 32768 + half * 16384;
        const unsigned short* src = isB ? Bb : Ab;
        const int ld = isB ? ldb : lda;
        const int kb = kt << 6;
#pragma unroll
        for (int l = 0; l < 2; l++) {
            int lam = l * 8192 + tid * 16;               // linear LDS byte in unit
            int lg  = lam ^ (((lam >> 7) & 7) << 4);     // pre-swizzled logical
            ASYNC_COPY16(src + (long)(half * 128 + (lg >> 7)) * ld + kb + ((lg & 127) >> 1),
                         dst + lam);
        }
    };

    auto phase = [&](int kt, int ks, int mh, int u, int vm_end) {
        const char* bA = sm + (kt & 1) * BUF;
        const char* bB = bA + 32768;
        const int ca = (ks * 64 + fk * 16) ^ ((fr & 7) << 4);
        short8 af[4], bf[4];
#pragma unroll
        for (int mi = 0; mi < 4; mi++) {
            int row = mh * 128 + wm * 64 + mi * 16 + fr;
            af[mi] = *(const short8*)(bA + row * 128 + ca);
        }
#pragma unroll
        for (int ni = 0; ni < 4; ni++) {
            int row = wn * 64 + ni * 16 + fr;
            bf[ni] = *(const short8*)(bB + row * 128 + ca);
        }
        if (kt + 1 < NKT) stage_unit(kt + 1, u);
        block_barrier();
        asm volatile("s_waitcnt lgkmcnt(0)" ::: "memory");
        __builtin_amdgcn_sched_barrier(0);
        __builtin_amdgcn_s_setprio(1);
#pragma unroll
        for (int mi = 0; mi < 4; mi++)
#pragma unroll
            for (int ni = 0; ni < 4; ni++)
                acc[mh * 4 + mi][ni] =
                    __builtin_amdgcn_mfma_f32_16x16x32_bf16(af[mi], bf[ni], acc[mh * 4 + mi][ni], 0, 0, 0);
        __builtin_amdgcn_s_setprio(0);
        if (vm_end == 2)      asm volatile("s_waitcnt vmcnt(2)" ::: "memory");
        else if (vm_end == 0) asm volatile("s_waitcnt vmcnt(0)" ::: "memory");
        block_barrier();
    };

    // prologue: stage tile 0 fully; publish Ah0,Bh0,Bh1 (keep Ah1 in flight)
    stage_unit(0, 0); stage_unit(0, 1); stage_unit(0, 2); stage_unit(0, 3);
    asm volatile("s_waitcnt vmcnt(2)" ::: "memory");
    block_barrier();

    for (int kt = 0; kt < NKT; kt++) {
        const bool more = (kt + 1 < NKT);
        phase(kt, 0, 0, 0, more ? 2 : 0);   // p0: end-wait publishes Ah1
        phase(kt, 0, 1, 1, -1);             // p1
        phase(kt, 1, 0, 2, -1);             // p2
        phase(kt, 1, 1, 3, more ? 2 : -1);  // p3: end-wait publishes next tile
    }

    const int crow = (lane >> 4) * 4;
    const int ccol = lane & 15;
#pragma unroll
    for (int a = 0; a < 8; a++) {
        const int mh = a >> 2, mi = a & 3;
#pragma unroll
        for (int j = 0; j < 4; j++) {
            long r = m0 + mh * 128 + wm * 64 + mi * 16 + crow + j;
            float rowf = 0.0f;
            if (EPI == 1) rowf = scale * aux[(long)blockIdx.z * sAux + r];  // scale*keep
#pragma unroll
            for (int ni = 0; ni < 4; ni++) {
                long c = n0 + wn * 64 + ni * 16 + ccol;
                float v = acc[a][ni][j];
                if (EPI == 0) {
                    ((unsigned short*)Cv)[(long)blockIdx.z * sC + r * ldc + c] = f2bf(v);
                } else {
                    ((unsigned short*)Cv)[(long)blockIdx.z * sC + r * ldc + c] = f2bf(__expf(v * rowf));
                }
            }
        }
    }
}

__global__ __launch_bounds__(512, 2) void gemm256_qkv(const unsigned short* __restrict__ A,
                                                      const unsigned short* __restrict__ B,
                                                      void* __restrict__ Cv,
                                                      int K, int lda, int ldb, int ldc,
                                                      long sA, long sB, long sC) {
    gemm256_body<0>(A, B, Cv, nullptr, K, lda, ldb, ldc, sA, sB, sC, 0L, 1.0f);
}

__global__ __launch_bounds__(512, 2) void gemm256_scores(const unsigned short* __restrict__ A,
                                                         const unsigned short* __restrict__ B,
                                                         void* __restrict__ Cv,
                                                         const float* __restrict__ keep,
                                                         int K, int lda, int ldb, int ldc,
                                                         long sA, long sB, long sC, long sAux,
                                                         float scale) {
    gemm256_body<1>(A, B, Cv, keep, K, lda, ldb, ldc, sA, sB, sC, sAux, scale);
}

// ---------------------------------------------------------------------------
// PV ring kernel (proven round-8 structure): 128x256, BK=32, depth-3 ring,
// one barrier per K-step, counted vmcnt, 64B-row swizzle. fp32 out * inv[row].
// ---------------------------------------------------------------------------
__global__ __launch_bounds__(512, 4) void gemm8_pv(const unsigned short* __restrict__ A,
                                                   const unsigned short* __restrict__ B,
                                                   void* __restrict__ Cv,
                                                   const float* __restrict__ invsum,
                                                   int K, int lda, int ldb, int ldc,
                                                   long sA, long sB, long sC, long sAux) {
    constexpr int TILE = (128 + 256) * 32 * 2;  // 24576 B per K-tile (A+B)
    __shared__ char sm[3 * TILE];

    const int tid = threadIdx.x;
    const int wid = tid >> 6, lane = tid & 63;
    const int wm  = wid >> 2, wn = wid & 3;
    const int fr  = lane & 15, fk = lane >> 4;
    const long m0 = (long)blockIdx.x * 128;
    const long n0 = (long)blockIdx.y * 256;
    const unsigned short* Ab = A + (long)blockIdx.z * sA + m0 * lda;
    const unsigned short* Bb = B + (long)blockIdx.z * sB + n0 * ldb;
    const int NT = K >> 5;

    floatx4 acc[4][4] = {};

    auto stage = [&](int kt, int buf) {
        char* dA = sm + buf * TILE;
        char* dB = dA + 128 * 64;
        const int kb = kt << 5;
        {
            int lam = tid * 16;
            int lg  = lam ^ (((lam >> 7) & 3) << 4);
            ASYNC_COPY16(Ab + (long)(lg >> 6) * lda + kb + ((lg & 63) >> 1), dA + lam);
        }
#pragma unroll
        for (int i = 0; i < 2; i++) {
            int lam = i * 8192 + tid * 16;
            int lg  = lam ^ (((lam >> 7) & 3) << 4);
            ASYNC_COPY16(Bb + (long)(lg >> 6) * ldb + kb + ((lg & 63) >> 1), dB + lam);
        }
    };

    stage(0, 0);
    stage(1, 1);

    int cur = 0;
    for (int t = 0; t < NT; t++) {
        if (t + 1 < NT) asm volatile("s_waitcnt vmcnt(3)" ::: "memory");
        else            asm volatile("s_waitcnt vmcnt(0)" ::: "memory");
        block_barrier();

        const char* bA = sm + cur * TILE;
        const char* bB = bA + 128 * 64;
        short8 af[4], bf[4];
#pragma unroll
        for (int mi = 0; mi < 4; mi++) {
            int row = wm * 64 + mi * 16 + fr;
            int c   = (fk * 16) ^ (((row >> 1) & 3) << 4);
            af[mi] = *(const short8*)(bA + row * 64 + c);
        }
#pragma unroll
        for (int ni = 0; ni < 4; ni++) {
            int row = wn * 64 + ni * 16 + fr;
            int c   = (fk * 16) ^ (((row >> 1) & 3) << 4);
            bf[ni] = *(const short8*)(bB + row * 64 + c);
        }
        if (t + 2 < NT) stage(t + 2, (cur + 2) % 3);

        __builtin_amdgcn_s_setprio(1);
#pragma unroll
        for (int mi = 0; mi < 4; mi++)
#pragma unroll
            for (int ni = 0; ni < 4; ni++)
                acc[mi][ni] = __builtin_amdgcn_mfma_f32_16x16x32_bf16(af[mi], bf[ni], acc[mi][ni], 0, 0, 0);
        __builtin_amdgcn_s_setprio(0);
        cur = (cur == 2) ? 0 : cur + 1;
    }

    const int crow = (lane >> 4) * 4;
    const int ccol = lane & 15;
#pragma unroll
    for (int mi = 0; mi < 4; mi++) {
#pragma unroll
        for (int j = 0; j < 4; j++) {
            long r = m0 + wm * 64 + mi * 16 + crow + j;
            float rowf = invsum[(long)blockIdx.z * sAux + r];
#pragma unroll
            for (int ni = 0; ni < 4; ni++) {
                long c = n0 + wn * 64 + ni * 16 + ccol;
                ((float*)Cv)[(long)blockIdx.z * sC + r * ldc + c] = acc[mi][ni][j] * rowf;
            }
        }
    }
}

// ---------------------------------------------------------------------------
__global__ __launch_bounds__(256) void rowsum_inv(const unsigned short* __restrict__ P,
                                                  float* __restrict__ inv, long strideP) {
    const int tid = threadIdx.x;
    const long row = blockIdx.x;
    short8 v = ((const short8*)(P + row * strideP))[tid];
    float s = 0.0f;
#pragma unroll
    for (int i = 0; i < 8; i++) s += bf2f((unsigned short)v[i]);
#pragma unroll
    for (int i = 1; i < 64; i <<= 1) s += __shfl_xor(s, i);
    __shared__ float ss[4];
    if ((tid & 63) == 0) ss[tid >> 6] = s;
    __syncthreads();
    if (tid == 0) {
        float t = (ss[0] + ss[1]) + (ss[2] + ss[3]);
        inv[row] = 1.0f / t;
    }
}

// ---------------------------------------------------------------------------
extern "C" void kernel_launch(void* const* d_in, const int* in_sizes, int n_in,
                              void* d_out, int out_size, void* d_ws, size_t ws_size,
                              hipStream_t stream) {
    const float* x  = (const float*)d_in[0];
    const void*  mask = d_in[1];
    const float* qw = (const float*)d_in[2];
    const float* kw = (const float*)d_in[3];
    const float* vw = (const float*)d_in[4];
    float* out = (float*)d_out;

    constexpr int B = 4, S = 2048, D = 1024;
    constexpr long BS  = (long)B * S;      // 8192
    constexpr long BSD = BS * D;           // 8388608

    char* w = (char*)d_ws;
    auto alloc = [&](size_t bytes) {
        char* p = w;
        w += (bytes + 255) & ~(size_t)255;
        return p;
    };
    int*            flag    = (int*)alloc(256);
    float*          keep    = (float*)alloc(BS * 4);
    float*          invsum  = (float*)alloc(BS * 4);
    unsigned short* xb      = (unsigned short*)alloc((size_t)BSD * 2);
    unsigned short* wT      = (unsigned short*)alloc((size_t)3 * D * D * 2);
    unsigned short* qkv     = (unsigned short*)alloc((size_t)3 * BSD * 2);
    unsigned short* Qb = qkv;
    unsigned short* Kb = qkv + BSD;
    unsigned short* Vb = qkv + 2 * BSD;
    unsigned short* Vt      = (unsigned short*)alloc((size_t)BSD * 2);

    size_t base_used = (size_t)(w - (char*)d_ws);
    size_t pB = (size_t)B * S * S * 2;  // 32 MiB unnormalized P (bf16)
    bool batched = ws_size >= base_used + pB + 1024;

    unsigned short* P;
    if (batched) {
        P = (unsigned short*)alloc(pB);
    } else {
        P = (unsigned short*)alloc((size_t)S * S * 2);
    }

    const float scale = 0.03125f;  // 1/sqrt(1024), exact

    mask_detect<<<1, 256, 0, stream>>>((const unsigned char*)mask, flag);
    mask_expand<<<(int)(BS / 256), 256, 0, stream>>>(mask, flag, keep, (int)BS);
    convert_f32_bf16<<<(int)(BSD / 1024), 256, 0, stream>>>(x, xb, BSD / 4);
    transpose_w_kernel<<<dim3(32, 32, 3), dim3(32, 8), 0, stream>>>(qw, kw, vw, wT);

    // Q,K,V projections: 256x256 tiles -> 32x4x3 = 384 blocks
    gemm256_qkv<<<dim3(32, 4, 3), 512, 0, stream>>>(xb, wT, qkv,
                                                    1024, 1024, 1024, 1024,
                                                    0L, (long)D * D, BSD);

    // V transpose: Vt[b][d][s]
    transpose_bf16<<<dim3(D / 32, S / 32, B), dim3(32, 8), 0, stream>>>(Vb, Vt, S, D,
                                                                        (long)S * D, (long)S * D);

    if (batched) {
        // P = exp(QK^T * scale * keep), bf16; 8x8x4 = 256 blocks (perfect fit)
        gemm256_scores<<<dim3(8, 8, B), 512, 0, stream>>>(Qb, Kb, P, keep,
                                                          1024, 1024, 1024, 2048,
                                                          (long)S * D, (long)S * D, (long)S * S, (long)S, scale);
        rowsum_inv<<<(int)BS, 256, 0, stream>>>(P, invsum, 2048);
        // out = (P * invsum[row]) . V   (128x256 ring -> 256 blocks)
        gemm8_pv<<<dim3(16, 4, B), 512, 0, stream>>>(P, Vt, out, invsum,
                                                     2048, 2048, 2048, 1024,
                                                     (long)S * S, (long)D * S, (long)S * D, (long)S);
    } else {
        for (int b = 0; b < B; b++) {
            gemm256_scores<<<dim3(8, 8, 1), 512, 0, stream>>>(Qb + (long)b * S * D, Kb + (long)b * S * D,
                                                              P, keep + (long)b * S,
                                                              1024, 1024, 1024, 2048,
                                                              0L, 0L, 0L, 0L, scale);
            rowsum_inv<<<S, 256, 0, stream>>>(P, invsum + (long)b * S, 2048);
            gemm8_pv<<<dim3(16, 4, 1), 512, 0, stream>>>(P, Vt + (long)b * D * S, out + (long)b * S * D,
                                                         invsum + (long)b * S,
                                                         2048, 2048, 2048, 1024,
                                                         0L, 0L, 0L, 0L);
        }
    }
}

// Round 10
// 182.446 us; speedup vs baseline: 1.0650x; 1.0650x over previous
//
#include <hip/hip_runtime.h>
#include <hip/hip_bf16.h>

typedef __attribute__((ext_vector_type(8))) short short8;
typedef __attribute__((ext_vector_type(4))) float floatx4;

struct ushort4v { unsigned short x, y, z, w; };

static __device__ __forceinline__ unsigned short f2bf(float f) {
    __hip_bfloat16 h = __float2bfloat16(f);
    return *reinterpret_cast<unsigned short*>(&h);
}

static __device__ __forceinline__ float bf2f(unsigned short u) {
    unsigned int v = ((unsigned int)u) << 16;
    return *reinterpret_cast<float*>(&v);
}

#define ASYNC_COPY16(gsrc, ldst)                                                            \
    __builtin_amdgcn_global_load_lds((const __attribute__((address_space(1))) void*)(gsrc), \
                                     (__attribute__((address_space(3))) void*)(ldst), 16, 0, 0)

static __device__ __forceinline__ void block_barrier() {
    asm volatile("" ::: "memory");
    __builtin_amdgcn_s_barrier();
    asm volatile("" ::: "memory");
}

// ---------------------------------------------------------------------------
__global__ void mask_detect(const unsigned char* __restrict__ m, int* __restrict__ flag) {
    __shared__ int s_or;
    if (threadIdx.x == 0) s_or = 0;
    __syncthreads();
    int acc = 0;
    for (int i = threadIdx.x; i < 8192; i += 256)
        if (i & 3) acc |= m[i];
    atomicOr(&s_or, acc);
    __syncthreads();
    if (threadIdx.x == 0) *flag = (s_or != 0) ? 1 : 0;  // 1 => u8 encoding
}

// keep[i] = 1.0f if attended, 0.0f if masked query row. exp(score*0)=1 for the
// whole row -> exactly-uniform softmax, identical to the reference where
// score*(1/32) + (-1e9) rounds to exactly -1e9 in fp32.
__global__ void mask_expand(const void* __restrict__ m, const int* __restrict__ flag,
                            float* __restrict__ keep, int n) {
    int i = blockIdx.x * 256 + threadIdx.x;
    if (i >= n) return;
    bool on;
    if (*flag)
        on = ((const unsigned char*)m)[i] != 0;
    else
        on = ((const int*)m)[i] != 0;
    keep[i] = on ? 1.0f : 0.0f;
}

// ---------------------------------------------------------------------------
__global__ __launch_bounds__(256) void convert_f32_bf16(const float* __restrict__ in,
                                                        unsigned short* __restrict__ out, long n4) {
    long i = (long)blockIdx.x * 256 + threadIdx.x;
    if (i >= n4) return;
    float4 v = ((const float4*)in)[i];
    ushort4v o;
    o.x = f2bf(v.x); o.y = f2bf(v.y); o.z = f2bf(v.z); o.w = f2bf(v.w);
    ((ushort4v*)out)[i] = o;
}

// ---------------------------------------------------------------------------
__global__ void transpose_w_kernel(const float* __restrict__ w0, const float* __restrict__ w1,
                                   const float* __restrict__ w2, unsigned short* __restrict__ out) {
    __shared__ float t[32][33];
    const float* w = blockIdx.z == 0 ? w0 : (blockIdx.z == 1 ? w1 : w2);
    unsigned short* o = out + (long)blockIdx.z * 1024 * 1024;
    int c0 = blockIdx.x * 32, r0 = blockIdx.y * 32;
    for (int i = threadIdx.y; i < 32; i += 8)
        t[i][threadIdx.x] = w[(long)(r0 + i) * 1024 + c0 + threadIdx.x];
    __syncthreads();
    for (int i = threadIdx.y; i < 32; i += 8)
        o[(long)(c0 + i) * 1024 + r0 + threadIdx.x] = f2bf(t[threadIdx.x][i]);
}

// ---------------------------------------------------------------------------
__global__ void transpose_bf16(const unsigned short* __restrict__ in, unsigned short* __restrict__ out,
                               int rows, int cols, long sIn, long sOut) {
    __shared__ unsigned short t[32][34];
    const unsigned short* ib = in + (long)blockIdx.z * sIn;
    unsigned short* ob = out + (long)blockIdx.z * sOut;
    int c0 = blockIdx.x * 32, r0 = blockIdx.y * 32;
    for (int i = threadIdx.y; i < 32; i += 8)
        t[i][threadIdx.x] = ib[(long)(r0 + i) * cols + c0 + threadIdx.x];
    __syncthreads();
    for (int i = threadIdx.y; i < 32; i += 8)
        ob[(long)(c0 + i) * rows + r0 + threadIdx.x] = t[threadIdx.x][i];
}

// ---------------------------------------------------------------------------
// Round-8 proven ring GEMM: C[M,N] = A[M,K] * BT[N,K]^T  (bf16 in, fp32 accum)
// 128x256 tile, BK=32, 8 waves (2M x 4N), per-wave 64x64 output.
// Depth-3 LDS ring (72KB -> 2 blocks/CU), ONE barrier per K-step:
//   {vmcnt(3|0), barrier, ds_read(t), stage(t+2 -> freed buf), MFMA(t)}
// LDS rows 64B: swizzle c ^= ((row>>1)&3)<<4 (involution, both sides).
// EPI 0: bf16 C; EPI 1: bf16 exp(acc*scale*keep[row]).
// ---------------------------------------------------------------------------
template <int EPI>
static __device__ __forceinline__ void gemm8_body(const unsigned short* __restrict__ A,
                                                  const unsigned short* __restrict__ B,
                                                  void* __restrict__ Cv,
                                                  const float* __restrict__ aux,
                                                  int K, int lda, int ldb, int ldc,
                                                  long sA, long sB, long sC, long sAux,
                                                  float scale) {
    constexpr int TILE = (128 + 256) * 32 * 2;  // 24576 B per K-tile (A+B)
    __shared__ char sm[3 * TILE];

    const int tid = threadIdx.x;
    const int wid = tid >> 6, lane = tid & 63;
    const int wm  = wid >> 2, wn = wid & 3;       // 2 x 4 wave grid
    const int fr  = lane & 15, fk = lane >> 4;    // fragment row / 16B col unit
    const long m0 = (long)blockIdx.x * 128;
    const long n0 = (long)blockIdx.y * 256;
    const unsigned short* Ab = A + (long)blockIdx.z * sA + m0 * lda;
    const unsigned short* Bb = B + (long)blockIdx.z * sB + n0 * ldb;
    const int NT = K >> 5;

    floatx4 acc[4][4] = {};

    auto stage = [&](int kt, int buf) {
        char* dA = sm + buf * TILE;
        char* dB = dA + 128 * 64;                 // A part = 8192 B
        const int kb = kt << 5;
        {
            int lam = tid * 16;                                // linear LDS byte
            int lg  = lam ^ (((lam >> 7) & 3) << 4);           // logical (involution)
            ASYNC_COPY16(Ab + (long)(lg >> 6) * lda + kb + ((lg & 63) >> 1), dA + lam);
        }
#pragma unroll
        for (int i = 0; i < 2; i++) {
            int lam = i * 8192 + tid * 16;
            int lg  = lam ^ (((lam >> 7) & 3) << 4);
            ASYNC_COPY16(Bb + (long)(lg >> 6) * ldb + kb + ((lg & 63) >> 1), dB + lam);
        }
    };

    stage(0, 0);
    stage(1, 1);

    int cur = 0;
    for (int t = 0; t < NT; t++) {
        if (t + 1 < NT) asm volatile("s_waitcnt vmcnt(3)" ::: "memory");
        else            asm volatile("s_waitcnt vmcnt(0)" ::: "memory");
        block_barrier();   // after this, every wave's reads of tile t-1 returned

        const char* bA = sm + cur * TILE;
        const char* bB = bA + 128 * 64;
        short8 af[4], bf[4];
#pragma unroll
        for (int mi = 0; mi < 4; mi++) {
            int row = wm * 64 + mi * 16 + fr;
            int c   = (fk * 16) ^ (((row >> 1) & 3) << 4);
            af[mi] = *(const short8*)(bA + row * 64 + c);
        }
#pragma unroll
        for (int ni = 0; ni < 4; ni++) {
            int row = wn * 64 + ni * 16 + fr;
            int c   = (fk * 16) ^ (((row >> 1) & 3) << 4);
            bf[ni] = *(const short8*)(bB + row * 64 + c);
        }
        if (t + 2 < NT) stage(t + 2, (cur + 2) % 3);   // refill buf freed at this barrier

        __builtin_amdgcn_s_setprio(1);
#pragma unroll
        for (int mi = 0; mi < 4; mi++)
#pragma unroll
            for (int ni = 0; ni < 4; ni++)
                acc[mi][ni] = __builtin_amdgcn_mfma_f32_16x16x32_bf16(af[mi], bf[ni], acc[mi][ni], 0, 0, 0);
        __builtin_amdgcn_s_setprio(0);
        cur = (cur == 2) ? 0 : cur + 1;
    }

    const int crow = (lane >> 4) * 4;
    const int ccol = lane & 15;
#pragma unroll
    for (int mi = 0; mi < 4; mi++) {
#pragma unroll
        for (int j = 0; j < 4; j++) {
            long r = m0 + wm * 64 + mi * 16 + crow + j;
            float rowf = 0.0f;
            if (EPI == 1) rowf = scale * aux[(long)blockIdx.z * sAux + r];  // scale*keep
#pragma unroll
            for (int ni = 0; ni < 4; ni++) {
                long c = n0 + wn * 64 + ni * 16 + ccol;
                float v = acc[mi][ni][j];
                if (EPI == 0) {
                    ((unsigned short*)Cv)[(long)blockIdx.z * sC + r * ldc + c] = f2bf(v);
                } else {
                    ((unsigned short*)Cv)[(long)blockIdx.z * sC + r * ldc + c] = f2bf(__expf(v * rowf));
                }
            }
        }
    }
}

__global__ __launch_bounds__(512, 4) void gemm8_qkv(const unsigned short* __restrict__ A,
                                                    const unsigned short* __restrict__ B,
                                                    void* __restrict__ Cv,
                                                    int K, int lda, int ldb, int ldc,
                                                    long sA, long sB, long sC) {
    gemm8_body<0>(A, B, Cv, nullptr, K, lda, ldb, ldc, sA, sB, sC, 0L, 1.0f);
}

__global__ __launch_bounds__(512, 4) void gemm8_scores(const unsigned short* __restrict__ A,
                                                       const unsigned short* __restrict__ B,
                                                       void* __restrict__ Cv,
                                                       const float* __restrict__ keep,
                                                       int K, int lda, int ldb, int ldc,
                                                       long sA, long sB, long sC, long sAux,
                                                       float scale) {
    gemm8_body<1>(A, B, Cv, keep, K, lda, ldb, ldc, sA, sB, sC, sAux, scale);
}

// ---------------------------------------------------------------------------
// PV: 4-wave 128x128 depth-3 ring. Per-wave 64x64 (same 16 MFMA per barrier
// as the 8-wave ring) but: barrier scope = 4 waves, TILE = 16KB, ring = 48KB
// -> 3 blocks/CU capacity; grid 512 blocks -> 2/CU co-resident (vs 1/CU for
// the 256-block 128x256 shape). Same 64B-row swizzle; 4 loads/stage ->
// counted vmcnt(4), tail vmcnt(0). fp32 out * invsum[row].
// ---------------------------------------------------------------------------
__global__ __launch_bounds__(256, 4) void gemm4_pv(const unsigned short* __restrict__ A,
                                                   const unsigned short* __restrict__ B,
                                                   void* __restrict__ Cv,
                                                   const float* __restrict__ invsum,
                                                   int K, int lda, int ldb, int ldc,
                                                   long sA, long sB, long sC, long sAux) {
    constexpr int TILE = (128 + 128) * 32 * 2;  // 16384 B per K-tile (A+B)
    __shared__ char sm[3 * TILE];

    const int tid = threadIdx.x;
    const int wid = tid >> 6, lane = tid & 63;
    const int wm  = wid >> 1, wn = wid & 1;       // 2 x 2 wave grid
    const int fr  = lane & 15, fk = lane >> 4;
    const long m0 = (long)blockIdx.x * 128;
    const long n0 = (long)blockIdx.y * 128;
    const unsigned short* Ab = A + (long)blockIdx.z * sA + m0 * lda;
    const unsigned short* Bb = B + (long)blockIdx.z * sB + n0 * ldb;
    const int NT = K >> 5;

    floatx4 acc[4][4] = {};

    auto stage = [&](int kt, int buf) {
        char* dA = sm + buf * TILE;
        char* dB = dA + 128 * 64;                 // A part = 8192 B
        const int kb = kt << 5;
#pragma unroll
        for (int i = 0; i < 2; i++) {
            int lam = i * 4096 + tid * 16;
            int lg  = lam ^ (((lam >> 7) & 3) << 4);
            ASYNC_COPY16(Ab + (long)(lg >> 6) * lda + kb + ((lg & 63) >> 1), dA + lam);
        }
#pragma unroll
        for (int i = 0; i < 2; i++) {
            int lam = i * 4096 + tid * 16;
            int lg  = lam ^ (((lam >> 7) & 3) << 4);
            ASYNC_COPY16(Bb + (long)(lg >> 6) * ldb + kb + ((lg & 63) >> 1), dB + lam);
        }
    };

    stage(0, 0);
    stage(1, 1);

    int cur = 0;
    for (int t = 0; t < NT; t++) {
        if (t + 1 < NT) asm volatile("s_waitcnt vmcnt(4)" ::: "memory");
        else            asm volatile("s_waitcnt vmcnt(0)" ::: "memory");
        block_barrier();

        const char* bA = sm + cur * TILE;
        const char* bB = bA + 128 * 64;
        short8 af[4], bf[4];
#pragma unroll
        for (int mi = 0; mi < 4; mi++) {
            int row = wm * 64 + mi * 16 + fr;
            int c   = (fk * 16) ^ (((row >> 1) & 3) << 4);
            af[mi] = *(const short8*)(bA + row * 64 + c);
        }
#pragma unroll
        for (int ni = 0; ni < 4; ni++) {
            int row = wn * 64 + ni * 16 + fr;
            int c   = (fk * 16) ^ (((row >> 1) & 3) << 4);
            bf[ni] = *(const short8*)(bB + row * 64 + c);
        }
        if (t + 2 < NT) stage(t + 2, (cur + 2) % 3);

        __builtin_amdgcn_s_setprio(1);
#pragma unroll
        for (int mi = 0; mi < 4; mi++)
#pragma unroll
            for (int ni = 0; ni < 4; ni++)
                acc[mi][ni] = __builtin_amdgcn_mfma_f32_16x16x32_bf16(af[mi], bf[ni], acc[mi][ni], 0, 0, 0);
        __builtin_amdgcn_s_setprio(0);
        cur = (cur == 2) ? 0 : cur + 1;
    }

    const int crow = (lane >> 4) * 4;
    const int ccol = lane & 15;
#pragma unroll
    for (int mi = 0; mi < 4; mi++) {
#pragma unroll
        for (int j = 0; j < 4; j++) {
            long r = m0 + wm * 64 + mi * 16 + crow + j;
            float rowf = invsum[(long)blockIdx.z * sAux + r];
#pragma unroll
            for (int ni = 0; ni < 4; ni++) {
                long c = n0 + wn * 64 + ni * 16 + ccol;
                ((float*)Cv)[(long)blockIdx.z * sC + r * ldc + c] = acc[mi][ni][j] * rowf;
            }
        }
    }
}

// ---------------------------------------------------------------------------
__global__ __launch_bounds__(256) void rowsum_inv(const unsigned short* __restrict__ P,
                                                  float* __restrict__ inv, long strideP) {
    const int tid = threadIdx.x;
    const long row = blockIdx.x;
    short8 v = ((const short8*)(P + row * strideP))[tid];
    float s = 0.0f;
#pragma unroll
    for (int i = 0; i < 8; i++) s += bf2f((unsigned short)v[i]);
#pragma unroll
    for (int i = 1; i < 64; i <<= 1) s += __shfl_xor(s, i);
    __shared__ float ss[4];
    if ((tid & 63) == 0) ss[tid >> 6] = s;
    __syncthreads();
    if (tid == 0) {
        float t = (ss[0] + ss[1]) + (ss[2] + ss[3]);
        inv[row] = 1.0f / t;
    }
}

// ---------------------------------------------------------------------------
extern "C" void kernel_launch(void* const* d_in, const int* in_sizes, int n_in,
                              void* d_out, int out_size, void* d_ws, size_t ws_size,
                              hipStream_t stream) {
    const float* x  = (const float*)d_in[0];
    const void*  mask = d_in[1];
    const float* qw = (const float*)d_in[2];
    const float* kw = (const float*)d_in[3];
    const float* vw = (const float*)d_in[4];
    float* out = (float*)d_out;

    constexpr int B = 4, S = 2048, D = 1024;
    constexpr long BS  = (long)B * S;      // 8192
    constexpr long BSD = BS * D;           // 8388608

    char* w = (char*)d_ws;
    auto alloc = [&](size_t bytes) {
        char* p = w;
        w += (bytes + 255) & ~(size_t)255;
        return p;
    };
    int*            flag    = (int*)alloc(256);
    float*          keep    = (float*)alloc(BS * 4);
    float*          invsum  = (float*)alloc(BS * 4);
    unsigned short* xb      = (unsigned short*)alloc((size_t)BSD * 2);
    unsigned short* wT      = (unsigned short*)alloc((size_t)3 * D * D * 2);
    unsigned short* qkv     = (unsigned short*)alloc((size_t)3 * BSD * 2);
    unsigned short* Qb = qkv;
    unsigned short* Kb = qkv + BSD;
    unsigned short* Vb = qkv + 2 * BSD;
    unsigned short* Vt      = (unsigned short*)alloc((size_t)BSD * 2);

    size_t base_used = (size_t)(w - (char*)d_ws);
    size_t pB = (size_t)B * S * S * 2;  // 32 MiB unnormalized P (bf16)
    bool batched = ws_size >= base_used + pB + 1024;

    unsigned short* P;
    if (batched) {
        P = (unsigned short*)alloc(pB);
    } else {
        P = (unsigned short*)alloc((size_t)S * S * 2);
    }

    const float scale = 0.03125f;  // 1/sqrt(1024), exact

    mask_detect<<<1, 256, 0, stream>>>((const unsigned char*)mask, flag);
    mask_expand<<<(int)(BS / 256), 256, 0, stream>>>(mask, flag, keep, (int)BS);
    convert_f32_bf16<<<(int)(BSD / 1024), 256, 0, stream>>>(x, xb, BSD / 4);
    transpose_w_kernel<<<dim3(32, 32, 3), dim3(32, 8), 0, stream>>>(qw, kw, vw, wT);

    // Q,K,V projections: 64x4x3 = 768 blocks, 2 blocks/CU
    gemm8_qkv<<<dim3(64, 4, 3), 512, 0, stream>>>(xb, wT, qkv,
                                                  1024, 1024, 1024, 1024,
                                                  0L, (long)D * D, BSD);

    // V transpose: Vt[b][d][s]
    transpose_bf16<<<dim3(D / 32, S / 32, B), dim3(32, 8), 0, stream>>>(Vb, Vt, S, D,
                                                                        (long)S * D, (long)S * D);

    if (batched) {
        // P = exp(QK^T * scale * keep), bf16  (512 blocks = one 2/CU round)
        gemm8_scores<<<dim3(16, 8, B), 512, 0, stream>>>(Qb, Kb, P, keep,
                                                         1024, 1024, 1024, 2048,
                                                         (long)S * D, (long)S * D, (long)S * S, (long)S, scale);
        rowsum_inv<<<(int)BS, 256, 0, stream>>>(P, invsum, 2048);
        // out = (P * invsum[row]) . V   (4-wave 128x128 -> 512 blocks, 2/CU)
        gemm4_pv<<<dim3(16, 8, B), 256, 0, stream>>>(P, Vt, out, invsum,
                                                     2048, 2048, 2048, 1024,
                                                     (long)S * S, (long)D * S, (long)S * D, (long)S);
    } else {
        for (int b = 0; b < B; b++) {
            gemm8_scores<<<dim3(16, 8, 1), 512, 0, stream>>>(Qb + (long)b * S * D, Kb + (long)b * S * D,
                                                             P, keep + (long)b * S,
                                                             1024, 1024, 1024, 2048,
                                                             0L, 0L, 0L, 0L, scale);
            rowsum_inv<<<S, 256, 0, stream>>>(P, invsum + (long)b * S, 2048);
            gemm4_pv<<<dim3(16, 8, 1), 256, 0, stream>>>(P, Vt + (long)b * D * S, out + (long)b * S * D,
                                                         invsum + (long)b * S,
                                                         2048, 2048, 2048, 1024,
                                                         0L, 0L, 0L, 0L);
        }
    }
}

// Round 13
// 171.354 us; speedup vs baseline: 1.1339x; 1.0647x over previous
//
#include <hip/hip_runtime.h>
#include <hip/hip_bf16.h>

typedef __attribute__((ext_vector_type(8))) short short8;
typedef __attribute__((ext_vector_type(4))) float floatx4;

struct ushort4v { unsigned short x, y, z, w; };

static __device__ __forceinline__ unsigned short f2bf(float f) {
    __hip_bfloat16 h = __float2bfloat16(f);
    return *reinterpret_cast<unsigned short*>(&h);
}

static __device__ __forceinline__ float bf2f(unsigned short u) {
    unsigned int v = ((unsigned int)u) << 16;
    return *reinterpret_cast<float*>(&v);
}

#define ASYNC_COPY16(gsrc, ldst)                                                            \
    __builtin_amdgcn_global_load_lds((const __attribute__((address_space(1))) void*)(gsrc), \
                                     (__attribute__((address_space(3))) void*)(ldst), 16, 0, 0)

static __device__ __forceinline__ void block_barrier() {
    asm volatile("" ::: "memory");
    __builtin_amdgcn_s_barrier();
    asm volatile("" ::: "memory");
}

// ---------------------------------------------------------------------------
// fused mask kernel: each block re-derives the bool encoding (u8 vs i32) from
// the first 8KB (L2-hot after block 0), then expands its slice.
// keep[i] = 1.0f attended, 0.0f masked row (exp(score*0)=1 -> uniform softmax,
// identical to reference where score/32 + (-1e9) rounds to exactly -1e9).
// ---------------------------------------------------------------------------
__global__ __launch_bounds__(256) void mask_expand_fused(const unsigned char* __restrict__ m,
                                                         float* __restrict__ keep, int n) {
    __shared__ int s_or;
    if (threadIdx.x == 0) s_or = 0;
    __syncthreads();
    int acc = 0;
    for (int i = threadIdx.x; i < 8192; i += 256)
        if (i & 3) acc |= m[i];
    atomicOr(&s_or, acc);
    __syncthreads();
    const bool u8enc = (s_or != 0);
    int i = blockIdx.x * 256 + threadIdx.x;
    if (i < n) {
        bool on = u8enc ? (m[i] != 0) : (((const int*)m)[i] != 0);
        keep[i] = on ? 1.0f : 0.0f;
    }
}

// ---------------------------------------------------------------------------
__global__ __launch_bounds__(256) void convert_f32_bf16(const float* __restrict__ in,
                                                        unsigned short* __restrict__ out, long n4) {
    long i = (long)blockIdx.x * 256 + threadIdx.x;
    if (i >= n4) return;
    float4 v = ((const float4*)in)[i];
    ushort4v o;
    o.x = f2bf(v.x); o.y = f2bf(v.y); o.z = f2bf(v.z); o.w = f2bf(v.w);
    ((ushort4v*)out)[i] = o;
}

// ---------------------------------------------------------------------------
__global__ void transpose_w_kernel(const float* __restrict__ w0, const float* __restrict__ w1,
                                   const float* __restrict__ w2, unsigned short* __restrict__ out) {
    __shared__ float t[32][33];
    const float* w = blockIdx.z == 0 ? w0 : (blockIdx.z == 1 ? w1 : w2);
    unsigned short* o = out + (long)blockIdx.z * 1024 * 1024;
    int c0 = blockIdx.x * 32, r0 = blockIdx.y * 32;
    for (int i = threadIdx.y; i < 32; i += 8)
        t[i][threadIdx.x] = w[(long)(r0 + i) * 1024 + c0 + threadIdx.x];
    __syncthreads();
    for (int i = threadIdx.y; i < 32; i += 8)
        o[(long)(c0 + i) * 1024 + r0 + threadIdx.x] = f2bf(t[threadIdx.x][i]);
}

// ---------------------------------------------------------------------------
// Ring GEMM (round-8 proven): C[M,N] = A[M,K] * BT[N,K]^T  (bf16, fp32 accum)
// 128x256 tile, BK=32, 8 waves, depth-3 LDS ring (72KB -> 2 blocks/CU),
// one barrier per K-step, counted vmcnt(3)/(0), 64B-row swizzle both sides.
// EPI 0: QKV — z<2 store bf16 C; z==2 store V TRANSPOSED to vt via LDS.
//   M axis is flattened b*S+s -> batch decompose: b = m0>>11, sloc = m0&2047
//   (blocks never straddle a batch: 2048 % 128 == 0). Same f2bf bits as the
//   old separate-transpose path -> bit-identical Vt.
// EPI 1: bf16 exp(acc*scale*keep[row]).   EPI 2: fp32 acc*invsum[row].
// ---------------------------------------------------------------------------
template <int EPI>
static __device__ __forceinline__ void gemm8_body(const unsigned short* __restrict__ A,
                                                  const unsigned short* __restrict__ B,
                                                  void* __restrict__ Cv,
                                                  unsigned short* __restrict__ vt,
                                                  const float* __restrict__ aux,
                                                  int K, int lda, int ldb, int ldc,
                                                  long sA, long sB, long sC, long sAux,
                                                  float scale) {
    constexpr int TILE = (128 + 256) * 32 * 2;  // 24576 B per K-tile (A+B)
    __shared__ char sm[3 * TILE];

    const int tid = threadIdx.x;
    const int wid = tid >> 6, lane = tid & 63;
    const int wm  = wid >> 2, wn = wid & 3;       // 2 x 4 wave grid
    const int fr  = lane & 15, fk = lane >> 4;
    const long m0 = (long)blockIdx.x * 128;
    const long n0 = (long)blockIdx.y * 256;
    const unsigned short* Ab = A + (long)blockIdx.z * sA + m0 * lda;
    const unsigned short* Bb = B + (long)blockIdx.z * sB + n0 * ldb;
    const int NT = K >> 5;

    floatx4 acc[4][4] = {};

    auto stage = [&](int kt, int buf) {
        char* dA = sm + buf * TILE;
        char* dB = dA + 128 * 64;                 // A part = 8192 B
        const int kb = kt << 5;
        {
            int lam = tid * 16;
            int lg  = lam ^ (((lam >> 7) & 3) << 4);
            ASYNC_COPY16(Ab + (long)(lg >> 6) * lda + kb + ((lg & 63) >> 1), dA + lam);
        }
#pragma unroll
        for (int i = 0; i < 2; i++) {
            int lam = i * 8192 + tid * 16;
            int lg  = lam ^ (((lam >> 7) & 3) << 4);
            ASYNC_COPY16(Bb + (long)(lg >> 6) * ldb + kb + ((lg & 63) >> 1), dB + lam);
        }
    };

    stage(0, 0);
    stage(1, 1);

    int cur = 0;
    for (int t = 0; t < NT; t++) {
        if (t + 1 < NT) asm volatile("s_waitcnt vmcnt(3)" ::: "memory");
        else            asm volatile("s_waitcnt vmcnt(0)" ::: "memory");
        block_barrier();   // after this, every wave's reads of tile t-1 returned

        const char* bA = sm + cur * TILE;
        const char* bB = bA + 128 * 64;
        short8 af[4], bf[4];
#pragma unroll
        for (int mi = 0; mi < 4; mi++) {
            int row = wm * 64 + mi * 16 + fr;
            int c   = (fk * 16) ^ (((row >> 1) & 3) << 4);
            af[mi] = *(const short8*)(bA + row * 64 + c);
        }
#pragma unroll
        for (int ni = 0; ni < 4; ni++) {
            int row = wn * 64 + ni * 16 + fr;
            int c   = (fk * 16) ^ (((row >> 1) & 3) << 4);
            bf[ni] = *(const short8*)(bB + row * 64 + c);
        }
        if (t + 2 < NT) stage(t + 2, (cur + 2) % 3);   // refill buf freed at this barrier

        __builtin_amdgcn_s_setprio(1);
#pragma unroll
        for (int mi = 0; mi < 4; mi++)
#pragma unroll
            for (int ni = 0; ni < 4; ni++)
                acc[mi][ni] = __builtin_amdgcn_mfma_f32_16x16x32_bf16(af[mi], bf[ni], acc[mi][ni], 0, 0, 0);
        __builtin_amdgcn_s_setprio(0);
        cur = (cur == 2) ? 0 : cur + 1;
    }

    const int crow = (lane >> 4) * 4;
    const int ccol = lane & 15;

    if (EPI == 0 && blockIdx.z == 2) {
        // V projection: emit TRANSPOSED via LDS. T[256 d][132 pad] bf16 = 67.6KB.
        block_barrier();   // all waves done with ring LDS
        unsigned short* T = (unsigned short*)sm;
        constexpr int LDT = 132;
#pragma unroll
        for (int mi = 0; mi < 4; mi++)
#pragma unroll
            for (int j = 0; j < 4; j++) {
                int rl = wm * 64 + mi * 16 + crow + j;      // s-local (0..127)
#pragma unroll
                for (int ni = 0; ni < 4; ni++) {
                    int cl = wn * 64 + ni * 16 + ccol;      // d-local (0..255)
                    T[cl * LDT + rl] = f2bf(acc[mi][ni][j]);
                }
            }
        block_barrier();
        // store Vt[b][d][s]: batch-decompose the flattened M index
        const long bb   = m0 >> 11;              // batch = m0 / 2048
        const long sloc = m0 & 2047;             // s offset within batch
        unsigned short* vb = vt + bb * (1024L * 2048) + sloc;
#pragma unroll
        for (int p = 0; p < 8; p++) {
            int chunk = p * 512 + tid;            // 0..4095
            int d  = chunk >> 4;                  // 256 rows x 16 chunks of 8
            int s0 = (chunk & 15) * 8;
            short8 v = *(const short8*)&T[d * LDT + s0];
            *(short8*)(vb + (n0 + d) * 2048 + s0) = v;
        }
        return;
    }

#pragma unroll
    for (int mi = 0; mi < 4; mi++) {
#pragma unroll
        for (int j = 0; j < 4; j++) {
            long r = m0 + wm * 64 + mi * 16 + crow + j;
            float rowf = 0.0f;
            if (EPI == 1) rowf = scale * aux[(long)blockIdx.z * sAux + r];  // scale*keep
            if (EPI == 2) rowf = aux[(long)blockIdx.z * sAux + r];          // invsum
#pragma unroll
            for (int ni = 0; ni < 4; ni++) {
                long c = n0 + wn * 64 + ni * 16 + ccol;
                float v = acc[mi][ni][j];
                if (EPI == 0) {
                    ((unsigned short*)Cv)[(long)blockIdx.z * sC + r * ldc + c] = f2bf(v);
                } else if (EPI == 1) {
                    ((unsigned short*)Cv)[(long)blockIdx.z * sC + r * ldc + c] = f2bf(__expf(v * rowf));
                } else {
                    ((float*)Cv)[(long)blockIdx.z * sC + r * ldc + c] = v * rowf;
                }
            }
        }
    }
}

__global__ __launch_bounds__(512, 4) void gemm8_qkv(const unsigned short* __restrict__ A,
                                                    const unsigned short* __restrict__ B,
                                                    void* __restrict__ Cv,
                                                    unsigned short* __restrict__ vt,
                                                    int K, int lda, int ldb, int ldc,
                                                    long sA, long sB, long sC) {
    gemm8_body<0>(A, B, Cv, vt, nullptr, K, lda, ldb, ldc, sA, sB, sC, 0L, 1.0f);
}

__global__ __launch_bounds__(512, 4) void gemm8_scores(const unsigned short* __restrict__ A,
                                                       const unsigned short* __restrict__ B,
                                                       void* __restrict__ Cv,
                                                       const float* __restrict__ keep,
                                                       int K, int lda, int ldb, int ldc,
                                                       long sA, long sB, long sC, long sAux,
                                                       float scale) {
    gemm8_body<1>(A, B, Cv, nullptr, keep, K, lda, ldb, ldc, sA, sB, sC, sAux, scale);
}

__global__ __launch_bounds__(512, 4) void gemm8_pv(const unsigned short* __restrict__ A,
                                                   const unsigned short* __restrict__ B,
                                                   void* __restrict__ Cv,
                                                   const float* __restrict__ invsum,
                                                   int K, int lda, int ldb, int ldc,
                                                   long sA, long sB, long sC, long sAux) {
    gemm8_body<2>(A, B, Cv, nullptr, invsum, K, lda, ldb, ldc, sA, sB, sC, sAux, 1.0f);
}

// ---------------------------------------------------------------------------
__global__ __launch_bounds__(256) void rowsum_inv(const unsigned short* __restrict__ P,
                                                  float* __restrict__ inv, long strideP) {
    const int tid = threadIdx.x;
    const long row = blockIdx.x;
    short8 v = ((const short8*)(P + row * strideP))[tid];
    float s = 0.0f;
#pragma unroll
    for (int i = 0; i < 8; i++) s += bf2f((unsigned short)v[i]);
#pragma unroll
    for (int i = 1; i < 64; i <<= 1) s += __shfl_xor(s, i);
    __shared__ float ss[4];
    if ((tid & 63) == 0) ss[tid >> 6] = s;
    __syncthreads();
    if (tid == 0) {
        float t = (ss[0] + ss[1]) + (ss[2] + ss[3]);
        inv[row] = 1.0f / t;
    }
}

// ---------------------------------------------------------------------------
extern "C" void kernel_launch(void* const* d_in, const int* in_sizes, int n_in,
                              void* d_out, int out_size, void* d_ws, size_t ws_size,
                              hipStream_t stream) {
    const float* x  = (const float*)d_in[0];
    const void*  mask = d_in[1];
    const float* qw = (const float*)d_in[2];
    const float* kw = (const float*)d_in[3];
    const float* vw = (const float*)d_in[4];
    float* out = (float*)d_out;

    constexpr int B = 4, S = 2048, D = 1024;
    constexpr long BS  = (long)B * S;      // 8192
    constexpr long BSD = BS * D;           // 8388608

    char* w = (char*)d_ws;
    auto alloc = [&](size_t bytes) {
        char* p = w;
        w += (bytes + 255) & ~(size_t)255;
        return p;
    };
    float*          keep    = (float*)alloc(BS * 4);
    float*          invsum  = (float*)alloc(BS * 4);
    unsigned short* xb      = (unsigned short*)alloc((size_t)BSD * 2);
    unsigned short* wT      = (unsigned short*)alloc((size_t)3 * D * D * 2);
    unsigned short* qk      = (unsigned short*)alloc((size_t)2 * BSD * 2);  // Q,K slabs
    unsigned short* Qb = qk;
    unsigned short* Kb = qk + BSD;
    unsigned short* Vt      = (unsigned short*)alloc((size_t)BSD * 2);      // V transposed [b][d][s]

    size_t base_used = (size_t)(w - (char*)d_ws);
    size_t pB = (size_t)B * S * S * 2;  // 32 MiB unnormalized P (bf16)
    bool batched = ws_size >= base_used + pB + 1024;

    unsigned short* P;
    if (batched) {
        P = (unsigned short*)alloc(pB);
    } else {
        P = (unsigned short*)alloc((size_t)S * S * 2);
    }

    const float scale = 0.03125f;  // 1/sqrt(1024), exact

    mask_expand_fused<<<(int)(BS / 256), 256, 0, stream>>>((const unsigned char*)mask, keep, (int)BS);
    convert_f32_bf16<<<(int)(BSD / 1024), 256, 0, stream>>>(x, xb, BSD / 4);
    transpose_w_kernel<<<dim3(32, 32, 3), dim3(32, 8), 0, stream>>>(qw, kw, vw, wT);

    // Q,K,V projections: z<2 -> qk slabs; z==2 -> Vt (transposed in-epilogue)
    gemm8_qkv<<<dim3(64, 4, 3), 512, 0, stream>>>(xb, wT, qk, Vt,
                                                  1024, 1024, 1024, 1024,
                                                  0L, (long)D * D, BSD);

    if (batched) {
        // P = exp(QK^T * scale * keep), bf16  (512 blocks = one 2/CU round)
        gemm8_scores<<<dim3(16, 8, B), 512, 0, stream>>>(Qb, Kb, P, keep,
                                                         1024, 1024, 1024, 2048,
                                                         (long)S * D, (long)S * D, (long)S * S, (long)S, scale);
        rowsum_inv<<<(int)BS, 256, 0, stream>>>(P, invsum, 2048);
        // out = (P * invsum[row]) . V   (8-wave ring, 256 blocks)
        gemm8_pv<<<dim3(16, 4, B), 512, 0, stream>>>(P, Vt, out, invsum,
                                                     2048, 2048, 2048, 1024,
                                                     (long)S * S, (long)D * S, (long)S * D, (long)S);
    } else {
        for (int b = 0; b < B; b++) {
            gemm8_scores<<<dim3(16, 8, 1), 512, 0, stream>>>(Qb + (long)b * S * D, Kb + (long)b * S * D,
                                                             P, keep + (long)b * S,
                                                             1024, 1024, 1024, 2048,
                                                             0L, 0L, 0L, 0L, scale);
            rowsum_inv<<<S, 256, 0, stream>>>(P, invsum + (long)b * S, 2048);
            gemm8_pv<<<dim3(16, 4, 1), 512, 0, stream>>>(P, Vt + (long)b * D * S, out + (long)b * S * D,
                                                         invsum + (long)b * S,
                                                         2048, 2048, 2048, 1024,
                                                         0L, 0L, 0L, 0L);
        }
    }
}